// Round 1
// baseline (228.337 us; speedup 1.0000x reference)
//
#include <hip/hip_runtime.h>

#define NB 4
#define NC 64
#define NH 256
#define NW 256
#define TH 16                  // output rows per block (each of 4 waves owns 4)
#define SROWS (TH + 6)         // staged input rows incl. +/-3 halo = 22
#define LROW 264               // LDS row: 4 zero-pad | 256 data | 4 zero-pad

// ---------- phase 1: per-pixel weight params, shared by all 64 channels ----------
// ws[pix] = {g, 1/S^2} with the exact op sequence of the fused kernel (bitwise same).
__global__ __launch_bounds__(256)
void wprep(const float* __restrict__ persp,
           const float* __restrict__ alpha_p,
           const float* __restrict__ beta_p,
           const float* __restrict__ gamma_p,
           float* __restrict__ ws)
{
    const float alpha = alpha_p[0];
    const float beta  = beta_p[0];
    const float gamma = gamma_p[0];
    const int i = (blockIdx.x * 256 + threadIdx.x) * 4;   // 256 blocks x 256 thr x 4 px
    const float4 p = *(const float4*)(persp + i);
    const float pa[4] = {p.x, p.y, p.z, p.w};
    float g[4], inv2[4];
    #pragma unroll
    for (int k = 0; k < 4; ++k) {
        const float z  = fmaf(beta, pa[k], gamma);
        const float sg = __builtin_amdgcn_rcpf(1.0f + __expf(-z));
        const float sigma = fmaxf(alpha * sg, 1e-4f);
        const float t  = 0.5f * __builtin_amdgcn_rcpf(sigma * sigma);
        const float gg = __expf(-t);
        const float g2 = gg * gg;
        const float p4 = g2 * g2;
        const float p9 = p4 * p4 * gg;
        const float S  = fmaf(2.0f, (gg + p4) + p9, 1.0f);
        const float inv = __builtin_amdgcn_rcpf(S);
        g[k] = gg;
        inv2[k] = inv * inv;
    }
    float* wp = ws + (size_t)i * 2;
    *(float4*)(wp)     = make_float4(g[0], inv2[0], g[1], inv2[1]);
    *(float4*)(wp + 4) = make_float4(g[2], inv2[2], g[3], inv2[3]);
}

// ---------- phase 2: 7x7 adaptive gaussian from LDS-staged tile ----------
__global__ __launch_bounds__(256, 4)
void adaptive_gauss7(const float* __restrict__ x,
                     const float* __restrict__ wsr,
                     float* __restrict__ out)
{
    __shared__ float lds[SROWS * LROW];   // 23,232 B -> up to 7 blocks/CU

    const int tid  = threadIdx.x;
    const int lane = tid & 63;
    const int wv   = tid >> 6;            // 4 waves x 4 rows = 16 rows
    const int c    = blockIdx.x;
    const int h0   = blockIdx.y * TH;
    const int b    = blockIdx.z;
    const int colbase = lane * 4;         // output cols colbase..colbase+3
    const int rg      = h0 + wv * 4;      // first output row of this wave

    const float* xc   = x   + (size_t)(b * NC + c) * NH * NW;
    float*       outp = out + (size_t)(b * NC + c) * NH * NW;
    const float* wrow = wsr + (size_t)b * NH * NW * 2;

    // ---- cooperative stage: 22 rows, zero side-pads, zero OOB rows ----
    if (tid < SROWS)
        *(float4*)&lds[tid * LROW] = make_float4(0.f, 0.f, 0.f, 0.f);
    else if (tid < 2 * SROWS)
        *(float4*)&lds[(tid - SROWS) * LROW + 260] = make_float4(0.f, 0.f, 0.f, 0.f);

    for (int r = wv; r < SROWS; r += 4) {
        const int gr = h0 - 3 + r;                       // wave-uniform condition
        float4 v = make_float4(0.f, 0.f, 0.f, 0.f);
        if ((unsigned)gr < NH)
            v = *(const float4*)(xc + (size_t)gr * NW + colbase);
        *(float4*)&lds[r * LROW + 4 + colbase] = v;
    }
    __syncthreads();

    // ---- weight pipeline: prefetch next row's (g, invS2) while computing ----
    const float* wp0 = wrow + ((size_t)rg * NW + colbase) * 2;
    float4 wa = *(const float4*)(wp0);          // {g0,i0,g1,i1}
    float4 wb = *(const float4*)(wp0 + 4);      // {g2,i2,g3,i3}

    #pragma unroll
    for (int o = 0; o < 4; ++o) {
        float4 na, nb;
        if (o < 3) {
            const float* wp = wrow + ((size_t)(rg + o + 1) * NW + colbase) * 2;
            na = *(const float4*)(wp);
            nb = *(const float4*)(wp + 4);
        }

        const float gk[4] = {wa.x, wa.z, wb.x, wb.z};
        const float iv[4] = {wa.y, wa.w, wb.y, wb.w};
        float g[4], p4[4], p9[4];
        #pragma unroll
        for (int k = 0; k < 4; ++k) {
            g[k] = gk[k];
            const float g2 = g[k] * g[k];
            p4[k] = g2 * g2;
            p9[k] = p4[k] * p4[k] * g[k];
        }

        // horizontal pass per input row (read 12 floats from LDS), kept in rs[7][4]
        float rs[7][4];
        #pragma unroll
        for (int j = 0; j < 7; ++j) {
            const float* rp = &lds[(wv * 4 + o + j) * LROW + colbase]; // cols colbase-4..+7
            const float4 r0 = *(const float4*)(rp);
            const float4 r1 = *(const float4*)(rp + 4);
            const float4 r2 = *(const float4*)(rp + 8);
            const float w[12] = {r0.x, r0.y, r0.z, r0.w,
                                 r1.x, r1.y, r1.z, r1.w,
                                 r2.x, r2.y, r2.z, r2.w};
            #pragma unroll
            for (int k = 0; k < 4; ++k) {
                rs[j][k] = fmaf(p9[k], w[k + 1] + w[k + 7],
                           fmaf(p4[k], w[k + 2] + w[k + 6],
                           fmaf(g[k],  w[k + 3] + w[k + 5],
                                       w[k + 4])));
            }
        }

        // vertical combine (same association as previous kernel -> bitwise identical)
        float res[4];
        #pragma unroll
        for (int k = 0; k < 4; ++k) {
            const float acc = fmaf(p9[k], rs[0][k] + rs[6][k],
                              fmaf(p4[k], rs[1][k] + rs[5][k],
                              fmaf(g[k],  rs[2][k] + rs[4][k],
                                          rs[3][k])));
            res[k] = acc * iv[k];
        }
        *(float4*)(outp + (size_t)(rg + o) * NW + colbase) =
            make_float4(res[0], res[1], res[2], res[3]);

        if (o < 3) { wa = na; wb = nb; }
    }
}

extern "C" void kernel_launch(void* const* d_in, const int* in_sizes, int n_in,
                              void* d_out, int out_size, void* d_ws, size_t ws_size,
                              hipStream_t stream) {
    const float* x     = (const float*)d_in[0];
    const float* persp = (const float*)d_in[1];
    const float* alpha = (const float*)d_in[2];
    const float* beta  = (const float*)d_in[3];
    const float* gamma = (const float*)d_in[4];
    float* outp        = (float*)d_out;
    float* ws          = (float*)d_ws;       // needs 4*256*256*2 floats = 2 MiB

    // phase 1: 262144 pixels / (256 thr * 4 px) = 256 blocks
    wprep<<<dim3((NB * NH * NW) / 1024), dim3(256), 0, stream>>>(persp, alpha, beta, gamma, ws);
    // phase 2: 64 x 16 x 4 = 4096 blocks, ~6-7 resident/CU
    adaptive_gauss7<<<dim3(NC, NH / TH, NB), dim3(256), 0, stream>>>(x, ws, outp);
}

// Round 2
// 137.572 us; speedup vs baseline: 1.6598x; 1.6598x over previous
//
#include <hip/hip_runtime.h>

#define NB 4
#define NC 64
#define NH 256
#define NW 256
#define TH 32                  // output rows per block (4 waves x 8 rows)
#define SROWS (TH + 6)         // 38 staged input rows (incl. +/-3 halo)
#define LROW 264               // LDS row: 4 zero-pad | 256 data | 4 zero-pad

// ---------- phase 1: per-pixel weight params, shared by all 64 channels ----------
// ws[pix] = {g, 1/S^2} with the exact op sequence round-0 used (same absmax).
__global__ __launch_bounds__(256)
void wprep(const float* __restrict__ persp,
           const float* __restrict__ alpha_p,
           const float* __restrict__ beta_p,
           const float* __restrict__ gamma_p,
           float* __restrict__ ws)
{
    const float alpha = alpha_p[0];
    const float beta  = beta_p[0];
    const float gamma = gamma_p[0];
    const int i = (blockIdx.x * 256 + threadIdx.x) * 4;
    const float4 p = *(const float4*)(persp + i);
    const float pa[4] = {p.x, p.y, p.z, p.w};
    float g[4], inv2[4];
    #pragma unroll
    for (int k = 0; k < 4; ++k) {
        const float z  = fmaf(beta, pa[k], gamma);
        const float sg = __builtin_amdgcn_rcpf(1.0f + __expf(-z));
        const float sigma = fmaxf(alpha * sg, 1e-4f);
        const float t  = 0.5f * __builtin_amdgcn_rcpf(sigma * sigma);
        const float gg = __expf(-t);
        const float g2 = gg * gg;
        const float p4 = g2 * g2;
        const float p9 = p4 * p4 * gg;
        const float S  = fmaf(2.0f, (gg + p4) + p9, 1.0f);
        const float inv = __builtin_amdgcn_rcpf(S);
        g[k] = gg;
        inv2[k] = inv * inv;
    }
    float* wp = ws + (size_t)i * 2;
    *(float4*)(wp)     = make_float4(g[0], inv2[0], g[1], inv2[1]);
    *(float4*)(wp + 4) = make_float4(g[2], inv2[2], g[3], inv2[3]);
}

// ---------- phase 2: async LDS stage + per-wave register window ----------
// NOTE: (256,2) only — round-1 lesson: tighter bounds force-spill (scratch
// writes showed as +218 MB WRITE_SIZE and scalarized LDS reads -> 8-way
// bank conflicts). Expect ~120-150 VGPR here, no scratch.
__global__ __launch_bounds__(256, 2)
void adaptive_gauss7(const float* __restrict__ x,
                     const float* __restrict__ wsr,
                     float* __restrict__ out)
{
    __shared__ float lds[SROWS * LROW];   // 40,128 B -> 4 blocks/CU by LDS

    const int tid  = threadIdx.x;
    const int lane = tid & 63;
    const int wv   = tid >> 6;            // 4 waves x 8 rows = 32 rows
    const int c    = blockIdx.x;
    const int h0   = blockIdx.y * TH;
    const int b    = blockIdx.z;
    const int colbase = lane * 4;         // output cols colbase..colbase+3
    const int rg      = h0 + wv * 8;      // first output row of this wave

    const float* xc   = x   + (size_t)(b * NC + c) * NH * NW;
    float*       outp = out + (size_t)(b * NC + c) * NH * NW;
    const float* wrow = wsr + (size_t)b * NH * NW * 2;

    // side pads: zero 4 floats at both ends of each staged row
    if (tid < SROWS) {
        *(float4*)&lds[tid * LROW]       = make_float4(0.f, 0.f, 0.f, 0.f);
        *(float4*)&lds[tid * LROW + 260] = make_float4(0.f, 0.f, 0.f, 0.f);
    }

    // async stage: each wave DMAs rows wv, wv+4, ... straight into LDS.
    // dest = wave-uniform base + lane*16 (linear, matches [r][4+colbase]).
    for (int r = wv; r < SROWS; r += 4) {
        const int gr = h0 - 3 + r;                     // wave-uniform bound
        if ((unsigned)gr < NH) {
            __builtin_amdgcn_global_load_lds(
                (const __attribute__((address_space(1))) void*)(xc + (size_t)gr * NW + colbase),
                (__attribute__((address_space(3))) void*)&lds[r * LROW + 4],
                16, 0, 0);
        } else {
            *(float4*)&lds[r * LROW + 4 + colbase] = make_float4(0.f, 0.f, 0.f, 0.f);
        }
    }
    __syncthreads();   // drains vmcnt (global_load_lds) + lgkmcnt

    // ---- register window over LDS: row (wv*8+o+j) lives in slot (o+j)%7 ----
    float win[7][12];
    #pragma unroll
    for (int r = 0; r < 7; ++r) {
        const float* rp = &lds[(wv * 8 + r) * LROW + colbase];  // cols colbase-4..+7
        const float4 a0 = *(const float4*)(rp);
        const float4 a1 = *(const float4*)(rp + 4);
        const float4 a2 = *(const float4*)(rp + 8);
        win[r][0] = a0.x; win[r][1] = a0.y; win[r][2]  = a0.z; win[r][3]  = a0.w;
        win[r][4] = a1.x; win[r][5] = a1.y; win[r][6]  = a1.z; win[r][7]  = a1.w;
        win[r][8] = a2.x; win[r][9] = a2.y; win[r][10] = a2.z; win[r][11] = a2.w;
    }

    const float* wp0 = wrow + ((size_t)rg * NW + colbase) * 2;
    float4 wa = *(const float4*)(wp0);          // {g0,i0,g1,i1}
    float4 wb = *(const float4*)(wp0 + 4);      // {g2,i2,g3,i3}

    #pragma unroll
    for (int o = 0; o < 8; ++o) {
        // (a) prefetch next input row from LDS (cheap latency, long distance)
        float nxt[12];
        if (o < 7) {
            const float* rp = &lds[(wv * 8 + o + 7) * LROW + colbase];
            const float4 a0 = *(const float4*)(rp);
            const float4 a1 = *(const float4*)(rp + 4);
            const float4 a2 = *(const float4*)(rp + 8);
            nxt[0] = a0.x; nxt[1] = a0.y; nxt[2]  = a0.z; nxt[3]  = a0.w;
            nxt[4] = a1.x; nxt[5] = a1.y; nxt[6]  = a1.z; nxt[7]  = a1.w;
            nxt[8] = a2.x; nxt[9] = a2.y; nxt[10] = a2.z; nxt[11] = a2.w;
        }
        // (b) prefetch next row's weight params
        float4 na, nb;
        if (o < 7) {
            const float* wp = wrow + ((size_t)(rg + o + 1) * NW + colbase) * 2;
            na = *(const float4*)(wp);
            nb = *(const float4*)(wp + 4);
        }

        // (c) compute output row rg+o
        const float gk[4] = {wa.x, wa.z, wb.x, wb.z};
        const float iv[4] = {wa.y, wa.w, wb.y, wb.w};
        float res[4];
        #pragma unroll
        for (int k = 0; k < 4; ++k) {
            const float g  = gk[k];
            const float g2 = g * g;
            const float p4 = g2 * g2;
            const float p9 = p4 * p4 * g;

            float rs[7];
            #pragma unroll
            for (int j = 0; j < 7; ++j) {
                const int s = (o + j) % 7;     // static after unroll
                rs[j] = fmaf(p9, win[s][k+1] + win[s][k+7],
                        fmaf(p4, win[s][k+2] + win[s][k+6],
                        fmaf(g,  win[s][k+3] + win[s][k+5],
                                 win[s][k+4])));
            }
            const float acc = fmaf(p9, rs[0] + rs[6],
                              fmaf(p4, rs[1] + rs[5],
                              fmaf(g,  rs[2] + rs[4],
                                       rs[3])));
            res[k] = acc * iv[k];
        }
        *(float4*)(outp + (size_t)(rg + o) * NW + colbase) =
            make_float4(res[0], res[1], res[2], res[3]);

        // (d) commit prefetched row into the dead slot
        if (o < 7) {
            #pragma unroll
            for (int q = 0; q < 12; ++q)
                win[o % 7][q] = nxt[q];
            wa = na; wb = nb;
        }
    }
}

extern "C" void kernel_launch(void* const* d_in, const int* in_sizes, int n_in,
                              void* d_out, int out_size, void* d_ws, size_t ws_size,
                              hipStream_t stream) {
    const float* x     = (const float*)d_in[0];
    const float* persp = (const float*)d_in[1];
    const float* alpha = (const float*)d_in[2];
    const float* beta  = (const float*)d_in[3];
    const float* gamma = (const float*)d_in[4];
    float* outp        = (float*)d_out;
    float* ws          = (float*)d_ws;       // 4*256*256*2 floats = 2 MiB

    wprep<<<dim3((NB * NH * NW) / 1024), dim3(256), 0, stream>>>(persp, alpha, beta, gamma, ws);
    adaptive_gauss7<<<dim3(NC, NH / TH, NB), dim3(256), 0, stream>>>(x, ws, outp);
}